// Round 10
// baseline (612.378 us; speedup 1.0000x reference)
//
#include <hip/hip_runtime.h>
#include <hip/hip_bf16.h>

#define BB 8
#define NN 1024
#define HH 512
#define NHEADS 8
#define UU 64

typedef __attribute__((ext_vector_type(8))) short short8;
typedef __attribute__((ext_vector_type(4))) float f32x4;
typedef unsigned short u16;
typedef unsigned char u8;

__device__ inline float b2f(unsigned short u) {
    union { float f; unsigned int i; } c; c.i = ((unsigned int)u) << 16; return c.f;
}
__device__ inline unsigned short f2b(float f) {
    __hip_bfloat16 h = __float2bfloat16(f);
    return *reinterpret_cast<unsigned short*>(&h);
}
__device__ inline void gl_lds16(const void* g, void* l) {
    __builtin_amdgcn_global_load_lds(
        (const __attribute__((address_space(1))) unsigned int*)g,
        (__attribute__((address_space(3))) unsigned int*)l, 16, 0, 0);
}

// ---------------------------------------------------------------------------
// K0: fp32 -> bf16 for the three W matrices.
// ---------------------------------------------------------------------------
__global__ __launch_bounds__(256) void cvt_w(
    const float* __restrict__ Wq, const float* __restrict__ Wk,
    const float* __restrict__ Wv, u16* __restrict__ Wb)
{
    const int which = blockIdx.y;
    const float* src = which == 0 ? Wq : (which == 1 ? Wk : Wv);
    u16* dst = Wb + (size_t)which * HH * HH;
    const int base = (blockIdx.x * 256 + threadIdx.x) * 8;
    const float4* sp = (const float4*)&src[base];
    float4 a = sp[0], b = sp[1];
    short8 o;
    o[0] = (short)f2b(a.x); o[1] = (short)f2b(a.y);
    o[2] = (short)f2b(a.z); o[3] = (short)f2b(a.w);
    o[4] = (short)f2b(b.x); o[5] = (short)f2b(b.y);
    o[6] = (short)f2b(b.z); o[7] = (short)f2b(b.w);
    *(short8*)&dst[base] = o;
}

// ---------------------------------------------------------------------------
// K0b: pack adj into bitmask adjp[row(8192)][dword(32)].
// ---------------------------------------------------------------------------
__global__ __launch_bounds__(256) void adj_pack(
    const int* __restrict__ adj, unsigned int* __restrict__ adjp)
{
    const int wave = threadIdx.x >> 6, lane = threadIdx.x & 63;
    const int row = blockIdx.x * 4 + wave;
    const int* ar = adj + (size_t)row * NN;
    unsigned long long* out = (unsigned long long*)(adjp + (size_t)row * 32);
    #pragma unroll
    for (int it = 0; it < 16; ++it) {
        int a = ar[it * 64 + lane];
        unsigned long long m = __ballot(a != 0);
        if (lane == 0) out[it] = m;
    }
}

// ---------------------------------------------------------------------------
// K1: qkv GEMM. 128x128 tile, BK=32; A from fp32 x (inline cvt, pitch 40),
// B via gl_lds16. Cs overlaps As/Bs in LDS (union) -> 35 KB -> 4 blocks/CU.
// ---------------------------------------------------------------------------
__global__ __launch_bounds__(256) void qkv_gemm(
    const float* __restrict__ x, const u16* __restrict__ Wb,
    const float* __restrict__ bq, const float* __restrict__ bk,
    const float* __restrict__ bv,
    u16* __restrict__ q, u16* __restrict__ k, u16* __restrict__ v)
{
    const int which = blockIdx.z;
    const u16* W      = Wb + (size_t)which * HH * HH;
    const float* bias = which == 0 ? bq : (which == 1 ? bk : bv);
    u16* out          = which == 0 ? q  : (which == 1 ? k  : v);

    const int tid = threadIdx.x;
    const int wave = tid >> 6, lane = tid & 63;
    const int ln = lane & 15, quad = lane >> 4;
    const int wr = (wave >> 1) * 64, wc = (wave & 1) * 64;
    const int rowbase = blockIdx.x * 128, colbase = blockIdx.y * 128;

    __shared__ __align__(16) u8 smem[128 * 136 * 2];   // Cs size (34816 B)
    u16* As = (u16*)smem;                 // 128*40*2 = 10240 B
    u16* Bs = (u16*)(smem + 10240);       // 128*32*2 =  8192 B
    u16* Cs = (u16*)smem;                 // overlaps (after barrier)

    f32x4 acc[4][4];
    #pragma unroll
    for (int ri = 0; ri < 4; ++ri)
        #pragma unroll
        for (int ci = 0; ci < 4; ++ci) acc[ri][ci] = (f32x4){0.f, 0.f, 0.f, 0.f};

    const int lr = lane >> 2;
    const int sg = lane & 3;

    for (int kk = 0; kk < HH; kk += 32) {
        __syncthreads();
        #pragma unroll
        for (int i = 0; i < 2; ++i) {
            int r = wave * 32 + i * 16 + lr;
            const float* xp = &x[(size_t)(rowbase + r) * HH + kk + sg * 8];
            float4 f0 = *(const float4*)xp, f1 = *(const float4*)(xp + 4);
            short8 o;
            o[0] = (short)f2b(f0.x); o[1] = (short)f2b(f0.y);
            o[2] = (short)f2b(f0.z); o[3] = (short)f2b(f0.w);
            o[4] = (short)f2b(f1.x); o[5] = (short)f2b(f1.y);
            o[6] = (short)f2b(f1.z); o[7] = (short)f2b(f1.w);
            *(short8*)&As[r * 40 + sg * 8] = o;
            gl_lds16(&W[(size_t)(colbase + r) * HH + kk + sg * 8],
                     (char*)Bs + (wave * 32 + i * 16) * 64);
        }
        __syncthreads();

        short8 bfr[4];
        #pragma unroll
        for (int ci = 0; ci < 4; ++ci)
            bfr[ci] = *(const short8*)&Bs[(wc + ci * 16 + ln) * 32 + quad * 8];
        #pragma unroll
        for (int ri = 0; ri < 4; ++ri) {
            short8 af = *(const short8*)&As[(wr + ri * 16 + ln) * 40 + quad * 8];
            #pragma unroll
            for (int ci = 0; ci < 4; ++ci)
                acc[ri][ci] = __builtin_amdgcn_mfma_f32_16x16x32_bf16(af, bfr[ci], acc[ri][ci], 0, 0, 0);
        }
    }

    __syncthreads();   // As/Bs dead; safe to overwrite via Cs
    #pragma unroll
    for (int ci = 0; ci < 4; ++ci) {
        int col = wc + ci * 16 + ln;
        float bb = bias[colbase + col];
        #pragma unroll
        for (int ri = 0; ri < 4; ++ri) {
            #pragma unroll
            for (int r = 0; r < 4; ++r) {
                int row = wr + ri * 16 + quad * 4 + r;
                Cs[row * 136 + col] = f2b(acc[ri][ci][r] + bb);
            }
        }
    }
    __syncthreads();
    {
        int row = tid >> 1, half = tid & 1;
        int gcol0 = colbase + half * 64;
        int hh = gcol0 >> 6;
        int grow = rowbase + row;
        int bidx = grow >> 10, n = grow & 1023;
        u16* op = &out[(((size_t)(bidx * NHEADS + hh)) * NN + n) * UU];
        const u16* cp = &Cs[row * 136 + half * 64];
        #pragma unroll
        for (int j = 0; j < 8; ++j)
            *(short8*)(op + j * 8) = *(const short8*)(cp + j * 8);
    }
}

// ---------------------------------------------------------------------------
// K2b: v (per-head bf16) -> v^T fp8: v8t[bh][d(64)][n(1024)].
// ---------------------------------------------------------------------------
__global__ __launch_bounds__(256) void vt8(
    const u16* __restrict__ v, u8* __restrict__ v8t)
{
    const int bh = blockIdx.x >> 2, part = blockIdx.x & 3;
    const int t = threadIdx.x;
    const size_t hd = (size_t)bh << 16;
    __shared__ u16 tile[64][72];

    for (int chunk = part * 4; chunk < part * 4 + 4; ++chunk) {
        const int n0 = chunk * 64;
        const int r = t >> 2, cs = t & 3;
        const u16* vp = &v[((size_t)bh * NN + n0 + r) * UU + cs * 16];
        short8 a = *(const short8*)vp;
        short8 b8 = *(const short8*)(vp + 8);
        #pragma unroll
        for (int j = 0; j < 8; ++j) {
            tile[r][cs * 16 + j] = (u16)a[j];
            tile[r][cs * 16 + 8 + j] = (u16)b8[j];
        }
        __syncthreads();
        const int c = t & 63, qt = t >> 6;
        unsigned int w[4];
        #pragma unroll
        for (int g = 0; g < 4; ++g) {
            float f0 = b2f(tile[qt * 16 + g * 4 + 0][c]);
            float f1 = b2f(tile[qt * 16 + g * 4 + 1][c]);
            float f2 = b2f(tile[qt * 16 + g * 4 + 2][c]);
            float f3 = b2f(tile[qt * 16 + g * 4 + 3][c]);
            int lo = __builtin_amdgcn_cvt_pk_fp8_f32(f0, f1, 0, false);
            w[g] = (unsigned int)__builtin_amdgcn_cvt_pk_fp8_f32(f2, f3, lo, true);
        }
        uint4 o; o.x = w[0]; o.y = w[1]; o.z = w[2]; o.w = w[3];
        *(uint4*)&v8t[hd + (size_t)c * 1024 + n0 + qt * 16] = o;
        __syncthreads();
    }
}

// ---------------------------------------------------------------------------
// K2: scores+softmax (unchanged from round 9).
// ---------------------------------------------------------------------------
__global__ __launch_bounds__(256) void scores_softmax(
    const u16* __restrict__ q, const u16* __restrict__ kmat,
    const unsigned int* __restrict__ adjp, u8* __restrict__ P8)
{
    const int b = blockIdx.z, h = blockIdx.y, rt = blockIdx.x;
    const int bh = b * NHEADS + h;
    const int tid = threadIdx.x;
    const int wave = tid >> 6, lane = tid & 63;
    const int ln = lane & 15, quad = lane >> 4;
    const int wrow = rt * 64 + wave * 16;

    __shared__ __align__(16) u16 ks[128 * 72];
    __shared__ __align__(16) u16 eb[64 * 136];

    const u16* qp = &q[((size_t)bh * NN + wrow + ln) * UU + quad * 8];
    short8 a0 = *(const short8*)qp;
    short8 a1 = *(const short8*)(qp + 32);

    float rsum[4] = {0.f, 0.f, 0.f, 0.f};
    float scl[4];

    const int srow = tid >> 3;
    const int sseg = tid & 7;

    for (int pass = 0; pass < 2; ++pass) {
        for (int cc = 0; cc < 8; ++cc) {
            __syncthreads();
            #pragma unroll
            for (int j = 0; j < 4; ++j) {
                int kr = j * 32 + srow;
                uint4 kv = *(const uint4*)&kmat[((size_t)bh * NN + cc * 128 + kr) * UU + sseg * 8];
                *(uint4*)&ks[kr * 72 + sseg * 8] = kv;
            }
            __syncthreads();

            unsigned int ab[4][4];
            #pragma unroll
            for (int r = 0; r < 4; ++r) {
                int row = wrow + quad * 4 + r;
                *(uint4*)&ab[r][0] =
                    *(const uint4*)&adjp[((size_t)(b * NN + row)) * 32 + cc * 4];
            }

            #pragma unroll
            for (int ct = 0; ct < 8; ++ct) {
                const u16* kp = &ks[(ct * 16 + ln) * 72 + quad * 8];
                short8 b0 = *(const short8*)kp;
                short8 b1 = *(const short8*)(kp + 32);
                f32x4 acc = (f32x4){0.f, 0.f, 0.f, 0.f};
                acc = __builtin_amdgcn_mfma_f32_16x16x32_bf16(a0, b0, acc, 0, 0, 0);
                acc = __builtin_amdgcn_mfma_f32_16x16x32_bf16(a1, b1, acc, 0, 0, 0);
                const int dw = ct >> 1;
                const int bitpos = (ct & 1) * 16 + ln;
                #pragma unroll
                for (int r = 0; r < 4; ++r) {
                    unsigned int on = (ab[r][dw] >> bitpos) & 1u;
                    float e = on ? __expf(acc[r] - 32.0f) : 0.0f;
                    if (pass == 0) rsum[r] += e;
                    else eb[(wave * 16 + quad * 4 + r) * 136 + ct * 16 + ln] = f2b(e * scl[r]);
                }
            }

            if (pass == 1) {
                const int kcp = lane >> 4, r16 = lane & 15;
                const u16* ep = &eb[(wave * 16 + r16) * 136 + kcp * 32];
                unsigned int w[8];
                #pragma unroll
                for (int g2 = 0; g2 < 4; ++g2) {
                    short8 ev = *(const short8*)(ep + g2 * 8);
                    float f0 = b2f((u16)ev[0]);
                    float f1 = b2f((u16)ev[1]);
                    float f2 = b2f((u16)ev[2]);
                    float f3 = b2f((u16)ev[3]);
                    int lo = __builtin_amdgcn_cvt_pk_fp8_f32(f0, f1, 0, false);
                    w[g2 * 2] = (unsigned int)__builtin_amdgcn_cvt_pk_fp8_f32(f2, f3, lo, true);
                    f0 = b2f((u16)ev[4]);
                    f1 = b2f((u16)ev[5]);
                    f2 = b2f((u16)ev[6]);
                    f3 = b2f((u16)ev[7]);
                    lo = __builtin_amdgcn_cvt_pk_fp8_f32(f0, f1, 0, false);
                    w[g2 * 2 + 1] = (unsigned int)__builtin_amdgcn_cvt_pk_fp8_f32(f2, f3, lo, true);
                }
                u8* op = P8 + ((size_t)bh << 20) + (size_t)(rt * 4 + wave) * 16384
                       + (cc * 4 + kcp) * 512 + r16 * 32;
                uint4 o0; o0.x = w[0]; o0.y = w[1]; o0.z = w[2]; o0.w = w[3];
                uint4 o1; o1.x = w[4]; o1.y = w[5]; o1.z = w[6]; o1.w = w[7];
                *(uint4*)op = o0;
                *(uint4*)(op + 16) = o1;
            }
        }
        if (pass == 0) {
            #pragma unroll
            for (int r = 0; r < 4; ++r) {
                #pragma unroll
                for (int off = 8; off >= 1; off >>= 1)
                    rsum[r] += __shfl_xor(rsum[r], off);
                scl[r] = 16.0f / rsum[r];
            }
        }
    }
}

// ---------------------------------------------------------------------------
// K3: persistent fused kernel: 4 hops + residual LayerNorm.
// Grid 512 x 512thr; LDS 65 KB => exactly 2 blocks/CU => all co-resident.
// Device-scope atomic barrier between phases. bar[8]: (cnt,flag) x 4.
// ---------------------------------------------------------------------------
__device__ inline void gbar(unsigned int* bar, int phase, unsigned int nblk) {
    __syncthreads();
    if (threadIdx.x == 0) {
        __threadfence();
        unsigned int arr = __hip_atomic_fetch_add(&bar[phase * 2], 1u,
                             __ATOMIC_ACQ_REL, __HIP_MEMORY_SCOPE_AGENT);
        if (arr == nblk - 1) {
            __hip_atomic_store(&bar[phase * 2 + 1], 1u,
                               __ATOMIC_RELEASE, __HIP_MEMORY_SCOPE_AGENT);
        } else {
            while (__hip_atomic_load(&bar[phase * 2 + 1],
                     __ATOMIC_ACQUIRE, __HIP_MEMORY_SCOPE_AGENT) == 0u)
                __builtin_amdgcn_s_sleep(8);
        }
        __threadfence();
    }
    __syncthreads();
}

__global__ __launch_bounds__(512, 4) void hops_ln(
    const u8* __restrict__ P8, const u8* __restrict__ v8t,
    const u16* __restrict__ v, u8* __restrict__ z8a, u8* __restrict__ z8b,
    u16* __restrict__ za, const float* __restrict__ x,
    const float* __restrict__ gamma, const float* __restrict__ beta,
    float* __restrict__ out, unsigned int* __restrict__ bar)
{
    const int blk = blockIdx.x;
    const int bh = blk >> 3, rt = blk & 7;
    const int b = bh >> 3, h = bh & 7;
    const int tid = threadIdx.x;
    const int wave = tid >> 6, lane = tid & 63;
    const int ln = lane & 15, quad = lane >> 4;
    const int wrow = rt * 128 + wave * 16;

    __shared__ __align__(16) u8 zt[64 * 1040];

    const u8* zins[4]  = { v8t, z8a, z8b, z8a };
    u8*       zouts[4] = { z8a, z8b, z8a, nullptr };

    for (int ph = 0; ph < 4; ++ph) {
        // stage z^T (64 KB) into LDS
        const u8* zg = zins[ph] + ((size_t)bh << 16);
        #pragma unroll
        for (int i = 0; i < 8; ++i) {
            int c = wave * 8 + i;
            gl_lds16(zg + (size_t)c * 1024 + lane * 16, (char*)zt + c * 1040);
        }
        __syncthreads();

        f32x4 acc[4];
        #pragma unroll
        for (int ci = 0; ci < 4; ++ci) acc[ci] = (f32x4){0.f, 0.f, 0.f, 0.f};

        const u8* pt = P8 + ((size_t)bh << 20) + (size_t)(rt * 8 + wave) * 16384
                     + ln * 32 + quad * 8;
        #pragma unroll 4
        for (int kc = 0; kc < 32; ++kc) {
            long a = *(const long*)(pt + kc * 512);
            int kk = kc * 32;
            #pragma unroll
            for (int ci = 0; ci < 4; ++ci) {
                long bz = *(const long*)&zt[(ci * 16 + ln) * 1040 + kk + quad * 8];
                acc[ci] = __builtin_amdgcn_mfma_f32_16x16x32_fp8_fp8(a, bz, acc[ci], 0, 0, 0);
            }
        }

        if (ph == 3) {
            #pragma unroll
            for (int ci = 0; ci < 4; ++ci) {
                int col = ci * 16 + ln;
                #pragma unroll
                for (int r = 0; r < 4; ++r) {
                    int row = wrow + quad * 4 + r;
                    float vv = b2f(v[((size_t)bh * NN + row) * UU + col]);
                    za[((size_t)(b * NN + row)) * HH + h * UU + col]
                        = f2b(0.05625f * acc[ci][r] + 0.1f * vv);
                }
            }
        } else {
            u8* zo = zouts[ph] + ((size_t)bh << 16);
            #pragma unroll
            for (int ci = 0; ci < 4; ++ci) {
                int col = ci * 16 + ln;
                float zv[4];
                #pragma unroll
                for (int r = 0; r < 4; ++r) {
                    int row = wrow + quad * 4 + r;
                    float vv = b2f(v[((size_t)bh * NN + row) * UU + col]);
                    zv[r] = 0.05625f * acc[ci][r] + 0.1f * vv;
                }
                int lo = __builtin_amdgcn_cvt_pk_fp8_f32(zv[0], zv[1], 0, false);
                unsigned int dw = (unsigned int)__builtin_amdgcn_cvt_pk_fp8_f32(zv[2], zv[3], lo, true);
                *(unsigned int*)&zo[(size_t)col * 1024 + wrow + quad * 4] = dw;
            }
        }
        gbar(bar, ph, gridDim.x);
    }

    // ---- residual + LayerNorm: block handles 16 rows (wave: rows wave, wave+8)
    const int r0 = blk * 16;
    for (int rr = wave; rr < 16; rr += 8) {
        const int row = r0 + rr;
        const size_t base = (size_t)row * HH + lane * 8;
        const float4* xp = (const float4*)&x[base];
        float4 x0 = xp[0], x1 = xp[1];
        short8 zv = *(const short8*)&za[base];
        float y[8];
        y[0] = x0.x + b2f((u16)zv[0]); y[1] = x0.y + b2f((u16)zv[1]);
        y[2] = x0.z + b2f((u16)zv[2]); y[3] = x0.w + b2f((u16)zv[3]);
        y[4] = x1.x + b2f((u16)zv[4]); y[5] = x1.y + b2f((u16)zv[5]);
        y[6] = x1.z + b2f((u16)zv[6]); y[7] = x1.w + b2f((u16)zv[7]);

        float s = 0.f, sq = 0.f;
        #pragma unroll
        for (int j = 0; j < 8; ++j) { s += y[j]; sq += y[j] * y[j]; }
        #pragma unroll
        for (int off = 32; off >= 1; off >>= 1) {
            s  += __shfl_xor(s, off);
            sq += __shfl_xor(sq, off);
        }
        const float mu = s * (1.0f / HH);
        const float var = sq * (1.0f / HH) - mu * mu;
        const float rstd = rsqrtf(var + 1e-5f);

        const float4* gp = (const float4*)&gamma[lane * 8];
        const float4* bp = (const float4*)&beta[lane * 8];
        float4 g0 = gp[0], g1 = gp[1], b0 = bp[0], b1 = bp[1];
        float4 o0, o1;
        o0.x = (y[0] - mu) * rstd * g0.x + b0.x;
        o0.y = (y[1] - mu) * rstd * g0.y + b0.y;
        o0.z = (y[2] - mu) * rstd * g0.z + b0.z;
        o0.w = (y[3] - mu) * rstd * g0.w + b0.w;
        o1.x = (y[4] - mu) * rstd * g1.x + b1.x;
        o1.y = (y[5] - mu) * rstd * g1.y + b1.y;
        o1.z = (y[6] - mu) * rstd * g1.z + b1.z;
        o1.w = (y[7] - mu) * rstd * g1.w + b1.w;
        float4* op = (float4*)&out[base];
        op[0] = o0; op[1] = o1;
    }
}

// ---------------------------------------------------------------------------
extern "C" void kernel_launch(void* const* d_in, const int* in_sizes, int n_in,
                              void* d_out, int out_size, void* d_ws, size_t ws_size,
                              hipStream_t stream)
{
    const float* x   = (const float*)d_in[0];
    const int* adj   = (const int*)d_in[1];
    const float* Wq  = (const float*)d_in[2];
    const float* bq  = (const float*)d_in[3];
    const float* Wk  = (const float*)d_in[4];
    const float* bk  = (const float*)d_in[5];
    const float* Wv  = (const float*)d_in[6];
    const float* bv  = (const float*)d_in[7];
    const float* gamma = (const float*)d_in[8];
    const float* beta  = (const float*)d_in[9];
    float* out = (float*)d_out;

    const size_t E = (size_t)BB * NN * HH;   // 4,194,304
    u16* ws16 = (u16*)d_ws;
    u16* q  = ws16 + E;      // per-head layout [bh][n][64]
    u16* k  = ws16 + 2 * E;
    u16* v  = ws16 + 3 * E;
    u16* za = ws16 + 4 * E;  // final z, bf16, [b,n,512]
    u16* Wb = ws16 + 5 * E;
    u8* base8 = (u8*)(ws16 + 5 * E + 786432);
    u8* P8  = base8;                          // 64 MB, tiled layout
    u8* z8a = base8 + ((size_t)64 << 20);
    u8* z8b = z8a + ((size_t)4 << 20);
    u8* v8t = z8b + ((size_t)4 << 20);
    unsigned int* adjp = (unsigned int*)(v8t + ((size_t)4 << 20));  // 1 MB
    unsigned int* bar  = (unsigned int*)((u8*)adjp + ((size_t)1 << 20));

    hipMemsetAsync(bar, 0, 64, stream);
    cvt_w<<<dim3(128, 3), 256, 0, stream>>>(Wq, Wk, Wv, Wb);
    adj_pack<<<dim3(2048), 256, 0, stream>>>(adj, adjp);
    qkv_gemm<<<dim3(64, 4, 3), 256, 0, stream>>>(x, Wb, bq, bk, bv, q, k, v);
    vt8<<<dim3(256), 256, 0, stream>>>(v, v8t);
    scores_softmax<<<dim3(16, NHEADS, BB), 256, 0, stream>>>(q, k, adjp, P8);
    hops_ln<<<dim3(512), 512, 0, stream>>>(P8, v8t, v, z8a, z8b, za,
                                           x, gamma, beta, out, bar);
}

// Round 11
// 289.054 us; speedup vs baseline: 2.1186x; 2.1186x over previous
//
#include <hip/hip_runtime.h>
#include <hip/hip_bf16.h>

#define BB 8
#define NN 1024
#define HH 512
#define NHEADS 8
#define UU 64

typedef __attribute__((ext_vector_type(8))) short short8;
typedef __attribute__((ext_vector_type(4))) float f32x4;
typedef unsigned short u16;
typedef unsigned char u8;

__device__ inline float b2f(unsigned short u) {
    union { float f; unsigned int i; } c; c.i = ((unsigned int)u) << 16; return c.f;
}
__device__ inline unsigned short f2b(float f) {
    __hip_bfloat16 h = __float2bfloat16(f);
    return *reinterpret_cast<unsigned short*>(&h);
}
__device__ inline void gl_lds16(const void* g, void* l) {
    __builtin_amdgcn_global_load_lds(
        (const __attribute__((address_space(1))) unsigned int*)g,
        (__attribute__((address_space(3))) unsigned int*)l, 16, 0, 0);
}

// ---------------------------------------------------------------------------
// K0: fp32 -> bf16 for the three W matrices.
// ---------------------------------------------------------------------------
__global__ __launch_bounds__(256) void cvt_w(
    const float* __restrict__ Wq, const float* __restrict__ Wk,
    const float* __restrict__ Wv, u16* __restrict__ Wb)
{
    const int which = blockIdx.y;
    const float* src = which == 0 ? Wq : (which == 1 ? Wk : Wv);
    u16* dst = Wb + (size_t)which * HH * HH;
    const int base = (blockIdx.x * 256 + threadIdx.x) * 8;
    const float4* sp = (const float4*)&src[base];
    float4 a = sp[0], b = sp[1];
    short8 o;
    o[0] = (short)f2b(a.x); o[1] = (short)f2b(a.y);
    o[2] = (short)f2b(a.z); o[3] = (short)f2b(a.w);
    o[4] = (short)f2b(b.x); o[5] = (short)f2b(b.y);
    o[6] = (short)f2b(b.z); o[7] = (short)f2b(b.w);
    *(short8*)&dst[base] = o;
}

// ---------------------------------------------------------------------------
// K0b: pack adj into bitmask adjp[row(8192)][dword(32)].
// ---------------------------------------------------------------------------
__global__ __launch_bounds__(256) void adj_pack(
    const int* __restrict__ adj, unsigned int* __restrict__ adjp)
{
    const int wave = threadIdx.x >> 6, lane = threadIdx.x & 63;
    const int row = blockIdx.x * 4 + wave;
    const int* ar = adj + (size_t)row * NN;
    unsigned long long* out = (unsigned long long*)(adjp + (size_t)row * 32);
    #pragma unroll
    for (int it = 0; it < 16; ++it) {
        int a = ar[it * 64 + lane];
        unsigned long long m = __ballot(a != 0);
        if (lane == 0) out[it] = m;
    }
}

// ---------------------------------------------------------------------------
// K1: qkv GEMM. 128x128 tile, BK=32; A from fp32 x (inline cvt, pitch 40),
// B via gl_lds16. Cs overlaps As/Bs (union) -> 35 KB -> 4 blocks/CU.
// Per-head output layout: out[(b*8+h)*1024+n][64].
// ---------------------------------------------------------------------------
__global__ __launch_bounds__(256) void qkv_gemm(
    const float* __restrict__ x, const u16* __restrict__ Wb,
    const float* __restrict__ bq, const float* __restrict__ bk,
    const float* __restrict__ bv,
    u16* __restrict__ q, u16* __restrict__ k, u16* __restrict__ v)
{
    const int which = blockIdx.z;
    const u16* W      = Wb + (size_t)which * HH * HH;
    const float* bias = which == 0 ? bq : (which == 1 ? bk : bv);
    u16* out          = which == 0 ? q  : (which == 1 ? k  : v);

    const int tid = threadIdx.x;
    const int wave = tid >> 6, lane = tid & 63;
    const int ln = lane & 15, quad = lane >> 4;
    const int wr = (wave >> 1) * 64, wc = (wave & 1) * 64;
    const int rowbase = blockIdx.x * 128, colbase = blockIdx.y * 128;

    __shared__ __align__(16) u8 smem[128 * 136 * 2];
    u16* As = (u16*)smem;                 // 10240 B
    u16* Bs = (u16*)(smem + 10240);       //  8192 B
    u16* Cs = (u16*)smem;                 // overlaps after barrier

    f32x4 acc[4][4];
    #pragma unroll
    for (int ri = 0; ri < 4; ++ri)
        #pragma unroll
        for (int ci = 0; ci < 4; ++ci) acc[ri][ci] = (f32x4){0.f, 0.f, 0.f, 0.f};

    const int lr = lane >> 2;
    const int sg = lane & 3;

    for (int kk = 0; kk < HH; kk += 32) {
        __syncthreads();
        #pragma unroll
        for (int i = 0; i < 2; ++i) {
            int r = wave * 32 + i * 16 + lr;
            const float* xp = &x[(size_t)(rowbase + r) * HH + kk + sg * 8];
            float4 f0 = *(const float4*)xp, f1 = *(const float4*)(xp + 4);
            short8 o;
            o[0] = (short)f2b(f0.x); o[1] = (short)f2b(f0.y);
            o[2] = (short)f2b(f0.z); o[3] = (short)f2b(f0.w);
            o[4] = (short)f2b(f1.x); o[5] = (short)f2b(f1.y);
            o[6] = (short)f2b(f1.z); o[7] = (short)f2b(f1.w);
            *(short8*)&As[r * 40 + sg * 8] = o;
            gl_lds16(&W[(size_t)(colbase + r) * HH + kk + sg * 8],
                     (char*)Bs + (wave * 32 + i * 16) * 64);
        }
        __syncthreads();

        short8 bfr[4];
        #pragma unroll
        for (int ci = 0; ci < 4; ++ci)
            bfr[ci] = *(const short8*)&Bs[(wc + ci * 16 + ln) * 32 + quad * 8];
        #pragma unroll
        for (int ri = 0; ri < 4; ++ri) {
            short8 af = *(const short8*)&As[(wr + ri * 16 + ln) * 40 + quad * 8];
            #pragma unroll
            for (int ci = 0; ci < 4; ++ci)
                acc[ri][ci] = __builtin_amdgcn_mfma_f32_16x16x32_bf16(af, bfr[ci], acc[ri][ci], 0, 0, 0);
        }
    }

    __syncthreads();
    #pragma unroll
    for (int ci = 0; ci < 4; ++ci) {
        int col = wc + ci * 16 + ln;
        float bb = bias[colbase + col];
        #pragma unroll
        for (int ri = 0; ri < 4; ++ri) {
            #pragma unroll
            for (int r = 0; r < 4; ++r) {
                int row = wr + ri * 16 + quad * 4 + r;
                Cs[row * 136 + col] = f2b(acc[ri][ci][r] + bb);
            }
        }
    }
    __syncthreads();
    {
        int row = tid >> 1, half = tid & 1;
        int gcol0 = colbase + half * 64;
        int hh = gcol0 >> 6;
        int grow = rowbase + row;
        int bidx = grow >> 10, n = grow & 1023;
        u16* op = &out[(((size_t)(bidx * NHEADS + hh)) * NN + n) * UU];
        const u16* cp = &Cs[row * 136 + half * 64];
        #pragma unroll
        for (int j = 0; j < 8; ++j)
            *(short8*)(op + j * 8) = *(const short8*)(cp + j * 8);
    }
}

// ---------------------------------------------------------------------------
// K2b: v (per-head bf16) -> v^T fp8: v8t[bh][d(64)][n(1024)].
// ---------------------------------------------------------------------------
__global__ __launch_bounds__(256) void vt8(
    const u16* __restrict__ v, u8* __restrict__ v8t)
{
    const int bh = blockIdx.x >> 2, part = blockIdx.x & 3;
    const int t = threadIdx.x;
    const size_t hd = (size_t)bh << 16;
    __shared__ u16 tile[64][72];

    for (int chunk = part * 4; chunk < part * 4 + 4; ++chunk) {
        const int n0 = chunk * 64;
        const int r = t >> 2, cs = t & 3;
        const u16* vp = &v[((size_t)bh * NN + n0 + r) * UU + cs * 16];
        short8 a = *(const short8*)vp;
        short8 b8 = *(const short8*)(vp + 8);
        #pragma unroll
        for (int j = 0; j < 8; ++j) {
            tile[r][cs * 16 + j] = (u16)a[j];
            tile[r][cs * 16 + 8 + j] = (u16)b8[j];
        }
        __syncthreads();
        const int c = t & 63, qt = t >> 6;
        unsigned int w[4];
        #pragma unroll
        for (int g = 0; g < 4; ++g) {
            float f0 = b2f(tile[qt * 16 + g * 4 + 0][c]);
            float f1 = b2f(tile[qt * 16 + g * 4 + 1][c]);
            float f2 = b2f(tile[qt * 16 + g * 4 + 2][c]);
            float f3 = b2f(tile[qt * 16 + g * 4 + 3][c]);
            int lo = __builtin_amdgcn_cvt_pk_fp8_f32(f0, f1, 0, false);
            w[g] = (unsigned int)__builtin_amdgcn_cvt_pk_fp8_f32(f2, f3, lo, true);
        }
        uint4 o; o.x = w[0]; o.y = w[1]; o.z = w[2]; o.w = w[3];
        *(uint4*)&v8t[hd + (size_t)c * 1024 + n0 + qt * 16] = o;
        __syncthreads();
    }
}

// ---------------------------------------------------------------------------
// K2: scores+softmax (round-9 version, unchanged).
// ---------------------------------------------------------------------------
__global__ __launch_bounds__(256) void scores_softmax(
    const u16* __restrict__ q, const u16* __restrict__ kmat,
    const unsigned int* __restrict__ adjp, u8* __restrict__ P8)
{
    const int b = blockIdx.z, h = blockIdx.y, rt = blockIdx.x;
    const int bh = b * NHEADS + h;
    const int tid = threadIdx.x;
    const int wave = tid >> 6, lane = tid & 63;
    const int ln = lane & 15, quad = lane >> 4;
    const int wrow = rt * 64 + wave * 16;

    __shared__ __align__(16) u16 ks[128 * 72];
    __shared__ __align__(16) u16 eb[64 * 136];

    const u16* qp = &q[((size_t)bh * NN + wrow + ln) * UU + quad * 8];
    short8 a0 = *(const short8*)qp;
    short8 a1 = *(const short8*)(qp + 32);

    float rsum[4] = {0.f, 0.f, 0.f, 0.f};
    float scl[4];

    const int srow = tid >> 3;
    const int sseg = tid & 7;

    for (int pass = 0; pass < 2; ++pass) {
        for (int cc = 0; cc < 8; ++cc) {
            __syncthreads();
            #pragma unroll
            for (int j = 0; j < 4; ++j) {
                int kr = j * 32 + srow;
                uint4 kv = *(const uint4*)&kmat[((size_t)bh * NN + cc * 128 + kr) * UU + sseg * 8];
                *(uint4*)&ks[kr * 72 + sseg * 8] = kv;
            }
            __syncthreads();

            unsigned int ab[4][4];
            #pragma unroll
            for (int r = 0; r < 4; ++r) {
                int row = wrow + quad * 4 + r;
                *(uint4*)&ab[r][0] =
                    *(const uint4*)&adjp[((size_t)(b * NN + row)) * 32 + cc * 4];
            }

            #pragma unroll
            for (int ct = 0; ct < 8; ++ct) {
                const u16* kp = &ks[(ct * 16 + ln) * 72 + quad * 8];
                short8 b0 = *(const short8*)kp;
                short8 b1 = *(const short8*)(kp + 32);
                f32x4 acc = (f32x4){0.f, 0.f, 0.f, 0.f};
                acc = __builtin_amdgcn_mfma_f32_16x16x32_bf16(a0, b0, acc, 0, 0, 0);
                acc = __builtin_amdgcn_mfma_f32_16x16x32_bf16(a1, b1, acc, 0, 0, 0);
                const int dw = ct >> 1;
                const int bitpos = (ct & 1) * 16 + ln;
                #pragma unroll
                for (int r = 0; r < 4; ++r) {
                    unsigned int on = (ab[r][dw] >> bitpos) & 1u;
                    float e = on ? __expf(acc[r] - 32.0f) : 0.0f;
                    if (pass == 0) rsum[r] += e;
                    else eb[(wave * 16 + quad * 4 + r) * 136 + ct * 16 + ln] = f2b(e * scl[r]);
                }
            }

            if (pass == 1) {
                const int kcp = lane >> 4, r16 = lane & 15;
                const u16* ep = &eb[(wave * 16 + r16) * 136 + kcp * 32];
                unsigned int w[8];
                #pragma unroll
                for (int g2 = 0; g2 < 4; ++g2) {
                    short8 ev = *(const short8*)(ep + g2 * 8);
                    float f0 = b2f((u16)ev[0]);
                    float f1 = b2f((u16)ev[1]);
                    float f2 = b2f((u16)ev[2]);
                    float f3 = b2f((u16)ev[3]);
                    int lo = __builtin_amdgcn_cvt_pk_fp8_f32(f0, f1, 0, false);
                    w[g2 * 2] = (unsigned int)__builtin_amdgcn_cvt_pk_fp8_f32(f2, f3, lo, true);
                    f0 = b2f((u16)ev[4]);
                    f1 = b2f((u16)ev[5]);
                    f2 = b2f((u16)ev[6]);
                    f3 = b2f((u16)ev[7]);
                    lo = __builtin_amdgcn_cvt_pk_fp8_f32(f0, f1, 0, false);
                    w[g2 * 2 + 1] = (unsigned int)__builtin_amdgcn_cvt_pk_fp8_f32(f2, f3, lo, true);
                }
                u8* op = P8 + ((size_t)bh << 20) + (size_t)(rt * 4 + wave) * 16384
                       + (cc * 4 + kcp) * 512 + r16 * 32;
                uint4 o0; o0.x = w[0]; o0.y = w[1]; o0.z = w[2]; o0.w = w[3];
                uint4 o1; o1.x = w[4]; o1.y = w[5]; o1.z = w[6]; o1.w = w[7];
                *(uint4*)op = o0;
                *(uint4*)(op + 16) = o1;
            }
        }
        if (pass == 0) {
            #pragma unroll
            for (int r = 0; r < 4; ++r) {
                #pragma unroll
                for (int off = 8; off >= 1; off >>= 1)
                    rsum[r] += __shfl_xor(rsum[r], off);
                scl[r] = 16.0f / rsum[r];
            }
        }
    }
}

// ---------------------------------------------------------------------------
// K3: hop: z' = (0.9/16) * P16 @ z + 0.1 * v.  P-load stream software-
// pipelined 4 deep (4-8 x 512B loads in flight per wave -> latency hidden).
// last=0: write z'^T fp8;  last=1: write z' bf16 in [b,n,512] layout.
// ---------------------------------------------------------------------------
__global__ __launch_bounds__(512) void hop(
    const u8* __restrict__ P8, const u8* __restrict__ z8in,
    const u16* __restrict__ v, u8* __restrict__ z8out,
    u16* __restrict__ zbf_out, int last)
{
    const int b = blockIdx.z, h = blockIdx.y, rt = blockIdx.x;
    const int bh = b * NHEADS + h;
    const int tid = threadIdx.x;
    const int wave = tid >> 6, lane = tid & 63;
    const int ln = lane & 15, quad = lane >> 4;
    const int wrow = rt * 128 + wave * 16;

    __shared__ __align__(16) u8 zt[64 * 1040];

    const u8* zg = z8in + ((size_t)bh << 16);
    #pragma unroll
    for (int i = 0; i < 8; ++i) {
        int c = wave * 8 + i;
        gl_lds16(zg + (size_t)c * 1024 + lane * 16, (char*)zt + c * 1040);
    }
    __syncthreads();

    f32x4 acc[4];
    #pragma unroll
    for (int ci = 0; ci < 4; ++ci) acc[ci] = (f32x4){0.f, 0.f, 0.f, 0.f};

    const u8* pt = P8 + ((size_t)bh << 20) + (size_t)(rt * 8 + wave) * 16384
                 + ln * 32 + quad * 8;

    long abuf[4];
    #pragma unroll
    for (int i = 0; i < 4; ++i) abuf[i] = *(const long*)(pt + i * 512);

    #pragma unroll
    for (int kb = 0; kb < 8; ++kb) {
        long an[4];
        if (kb < 7) {
            #pragma unroll
            for (int i = 0; i < 4; ++i)
                an[i] = *(const long*)(pt + (kb * 4 + 4 + i) * 512);
        }
        #pragma unroll
        for (int i = 0; i < 4; ++i) {
            const int kk = (kb * 4 + i) * 32;
            #pragma unroll
            for (int ci = 0; ci < 4; ++ci) {
                long bz = *(const long*)&zt[(ci * 16 + ln) * 1040 + kk + quad * 8];
                acc[ci] = __builtin_amdgcn_mfma_f32_16x16x32_fp8_fp8(abuf[i], bz, acc[ci], 0, 0, 0);
            }
        }
        #pragma unroll
        for (int i = 0; i < 4; ++i) abuf[i] = an[i];
    }

    if (last) {
        #pragma unroll
        for (int ci = 0; ci < 4; ++ci) {
            int col = ci * 16 + ln;
            #pragma unroll
            for (int r = 0; r < 4; ++r) {
                int row = wrow + quad * 4 + r;
                float vv = b2f(v[((size_t)bh * NN + row) * UU + col]);
                zbf_out[((size_t)(b * NN + row)) * HH + h * UU + col]
                    = f2b(0.05625f * acc[ci][r] + 0.1f * vv);
            }
        }
    } else {
        u8* zo = z8out + ((size_t)bh << 16);
        #pragma unroll
        for (int ci = 0; ci < 4; ++ci) {
            int col = ci * 16 + ln;
            float zv[4];
            #pragma unroll
            for (int r = 0; r < 4; ++r) {
                int row = wrow + quad * 4 + r;
                float vv = b2f(v[((size_t)bh * NN + row) * UU + col]);
                zv[r] = 0.05625f * acc[ci][r] + 0.1f * vv;
            }
            int lo = __builtin_amdgcn_cvt_pk_fp8_f32(zv[0], zv[1], 0, false);
            unsigned int dw = (unsigned int)__builtin_amdgcn_cvt_pk_fp8_f32(zv[2], zv[3], lo, true);
            *(unsigned int*)&zo[(size_t)col * 1024 + wrow + quad * 4] = dw;
        }
    }
}

// ---------------------------------------------------------------------------
// K4: y = x + z ; LayerNorm(y)*gamma + beta. x fp32, z bf16 [b,n,512], out fp32.
// ---------------------------------------------------------------------------
__global__ __launch_bounds__(256) void resid_ln(
    const float* __restrict__ x, const u16* __restrict__ z,
    const float* __restrict__ gamma, const float* __restrict__ beta,
    float* __restrict__ out)
{
    const int r = blockIdx.x * 4 + (threadIdx.x >> 6);
    const int lane = threadIdx.x & 63;
    const size_t base = (size_t)r * HH + lane * 8;

    const float4* xp = (const float4*)&x[base];
    float4 x0 = xp[0], x1 = xp[1];
    short8 zv = *(const short8*)&z[base];
    float y[8];
    y[0] = x0.x + b2f((u16)zv[0]); y[1] = x0.y + b2f((u16)zv[1]);
    y[2] = x0.z + b2f((u16)zv[2]); y[3] = x0.w + b2f((u16)zv[3]);
    y[4] = x1.x + b2f((u16)zv[4]); y[5] = x1.y + b2f((u16)zv[5]);
    y[6] = x1.z + b2f((u16)zv[6]); y[7] = x1.w + b2f((u16)zv[7]);

    float s = 0.f, sq = 0.f;
    #pragma unroll
    for (int j = 0; j < 8; ++j) { s += y[j]; sq += y[j] * y[j]; }
    #pragma unroll
    for (int off = 32; off >= 1; off >>= 1) {
        s  += __shfl_xor(s, off);
        sq += __shfl_xor(sq, off);
    }
    const float mu = s * (1.0f / HH);
    const float var = sq * (1.0f / HH) - mu * mu;
    const float rstd = rsqrtf(var + 1e-5f);

    const float4* gp = (const float4*)&gamma[lane * 8];
    const float4* bp = (const float4*)&beta[lane * 8];
    float4 g0 = gp[0], g1 = gp[1], b0 = bp[0], b1 = bp[1];

    float4 o0, o1;
    o0.x = (y[0] - mu) * rstd * g0.x + b0.x;
    o0.y = (y[1] - mu) * rstd * g0.y + b0.y;
    o0.z = (y[2] - mu) * rstd * g0.z + b0.z;
    o0.w = (y[3] - mu) * rstd * g0.w + b0.w;
    o1.x = (y[4] - mu) * rstd * g1.x + b1.x;
    o1.y = (y[5] - mu) * rstd * g1.y + b1.y;
    o1.z = (y[6] - mu) * rstd * g1.z + b1.z;
    o1.w = (y[7] - mu) * rstd * g1.w + b1.w;
    float4* op = (float4*)&out[base];
    op[0] = o0; op[1] = o1;
}

// ---------------------------------------------------------------------------
extern "C" void kernel_launch(void* const* d_in, const int* in_sizes, int n_in,
                              void* d_out, int out_size, void* d_ws, size_t ws_size,
                              hipStream_t stream)
{
    const float* x   = (const float*)d_in[0];
    const int* adj   = (const int*)d_in[1];
    const float* Wq  = (const float*)d_in[2];
    const float* bq  = (const float*)d_in[3];
    const float* Wk  = (const float*)d_in[4];
    const float* bk  = (const float*)d_in[5];
    const float* Wv  = (const float*)d_in[6];
    const float* bv  = (const float*)d_in[7];
    const float* gamma = (const float*)d_in[8];
    const float* beta  = (const float*)d_in[9];
    float* out = (float*)d_out;

    const size_t E = (size_t)BB * NN * HH;   // 4,194,304
    u16* ws16 = (u16*)d_ws;
    u16* q  = ws16 + E;      // per-head layout [bh][n][64]
    u16* k  = ws16 + 2 * E;
    u16* v  = ws16 + 3 * E;
    u16* za = ws16 + 4 * E;  // final z, bf16, [b,n,512]
    u16* Wb = ws16 + 5 * E;
    u8* base8 = (u8*)(ws16 + 5 * E + 786432);
    u8* P8  = base8;                          // 64 MB, tiled layout
    u8* z8a = base8 + ((size_t)64 << 20);
    u8* z8b = z8a + ((size_t)4 << 20);
    u8* v8t = z8b + ((size_t)4 << 20);
    unsigned int* adjp = (unsigned int*)(v8t + ((size_t)4 << 20));  // 1 MB

    cvt_w<<<dim3(128, 3), 256, 0, stream>>>(Wq, Wk, Wv, Wb);
    adj_pack<<<dim3(2048), 256, 0, stream>>>(adj, adjp);
    qkv_gemm<<<dim3(64, 4, 3), 256, 0, stream>>>(x, Wb, bq, bk, bv, q, k, v);
    vt8<<<dim3(256), 256, 0, stream>>>(v, v8t);
    scores_softmax<<<dim3(16, NHEADS, BB), 256, 0, stream>>>(q, k, adjp, P8);
    hop<<<dim3(8, NHEADS, BB), 512, 0, stream>>>(P8, v8t, v, z8a, za, 0);
    hop<<<dim3(8, NHEADS, BB), 512, 0, stream>>>(P8, z8a, v, z8b, za, 0);
    hop<<<dim3(8, NHEADS, BB), 512, 0, stream>>>(P8, z8b, v, z8a, za, 0);
    hop<<<dim3(8, NHEADS, BB), 512, 0, stream>>>(P8, z8a, v, z8b, za, 1);
    resid_ln<<<dim3(2048), 256, 0, stream>>>(x, za, gamma, beta, out);
}